// Round 4
// baseline (2200.907 us; speedup 1.0000x reference)
//
#include <hip/hip_runtime.h>
#include <hip/hip_bf16.h>

// GCNBlock: TransformerConv(32 heads, dim 8, edge_dim 64) + EdgeResidualLayer
// N=50000, E=400000, D_NODE=256, D_EDGE=64.
// Dtypes (established round 2/3 evidence): float tensors are FP32 (in & out),
// edge_index int64 (k0 detects and normalizes to int32 anyway).
// Internals: bf16 MFMA with fp32 accumulate; bf16 ws intermediates.
//
//  k0/k0b: edge_index -> int32 [src|dst]
//  kT : We^T, perm(W1)^T, W2^T as bf16 in ws
//  k1 : q,k,v = x@W*+b (bf16 ws), skip = x@Ws+bs (fp32, staged in out_e region)
//  k2 : per 64-edge tile: eproj = ea@We via MFMA -> LDS; per-wave 16-edge
//       attention: alpha=q[dst]·(k[src]+e)/sqrt8, ex=exp(alpha),
//       atomicAdd denom[dst,h], msg[dst,:] += (v[src]+e)*ex
//       (softmax normalization commutes with the segment sum; |alpha|<~3)
//  k3 : x_new = leaky(msg/denom + skip) -> out_x fp32 + bf16 copy in ws
//  k4 : edge MLP via 2 MFMA GEMMs on [ea|x_s|x_d] tiles, out_e fp32
//
// ws layout (138.4 MB):
//   flags@0, es32@4096, ed32@1604096, WeT@3.4M, W1Tp@3.5M, W2T@3.6M,
//   qb/xnb@4M (bf16), kb@29.6M, vb@55.2M, msg fp32@80.8M, denom fp32@132M

#define N_NODES 50000
#define N_EDGES 400000
#define D_NODE 256
#define D_EDGE 64
#define HEADS 32
#define LRELU 0.01f

typedef __hip_bfloat16 bf16;
typedef __attribute__((ext_vector_type(8))) short short8b;          // 8 bf16
typedef __attribute__((ext_vector_type(4))) float f32x4;
typedef __attribute__((ext_vector_type(4))) unsigned short ushort4v;

__device__ __forceinline__ float bf2f(bf16 v) { return __bfloat162float(v); }
__device__ __forceinline__ bf16 f2bf(float f) { return __float2bfloat16(f); }
__device__ __forceinline__ float bfraw(unsigned short u) {
    return __uint_as_float(((unsigned int)u) << 16);
}
__device__ __forceinline__ unsigned short rawbf(float f) {
    bf16 t = f2bf(f); return *(unsigned short*)&t;
}
__device__ __forceinline__ float leaky(float v) { return v >= 0.f ? v : LRELU * v; }

// ---------------- k0: index width detection (1 wave) ----------------
__global__ void k0_detect(const int* __restrict__ ei, int* __restrict__ flags)
{
    const int lane = threadIdx.x;
    const unsigned long long mz = __ballot(ei[2 * lane + 1] == 0);
    if (lane == 0) flags[0] = (__popcll(mz) >= 48) ? 1 : 0;   // 1 => int64
}

__global__ __launch_bounds__(256) void k0b_edges(
    const int* __restrict__ ei, const int* __restrict__ flags,
    int* __restrict__ es32, int* __restrict__ ed32)
{
    const int i = blockIdx.x * 256 + threadIdx.x;
    if (i >= N_EDGES) return;
    if (flags[0]) {
        const long long* e64 = (const long long*)ei;
        es32[i] = (int)e64[i];
        ed32[i] = (int)e64[N_EDGES + i];
    } else {
        es32[i] = ei[i];
        ed32[i] = ei[N_EDGES + i];
    }
}

// ---------------- kT: weight transposes (fp32 -> bf16) ----------------
// WeT[n][k]=We[k][n]; W1Tp[n][k']=W1[perm(k')][n], perm(k')=k'<64?512+k':k'-64
// (h rows are [ea|x_s|x_d]); W2T[n][k]=W2[k][n]
__global__ __launch_bounds__(256) void kT_transpose(
    const float* __restrict__ We, const float* __restrict__ W1, const float* __restrict__ W2,
    bf16* __restrict__ WeT, bf16* __restrict__ W1Tp, bf16* __restrict__ W2T)
{
    const int tid = threadIdx.x;
    for (int i = tid; i < 256 * 64; i += 256) {
        const int n = i >> 6, k = i & 63;
        WeT[i] = f2bf(We[k * 256 + n]);
    }
    for (int i = tid; i < 64 * 576; i += 256) {
        const int n = i / 576, kp = i % 576;
        const int k = (kp < 64) ? (512 + kp) : (kp - 64);
        W1Tp[i] = f2bf(W1[k * 64 + n]);
    }
    for (int i = tid; i < 64 * 64; i += 256) {
        const int n = i >> 6, k = i & 63;
        W2T[i] = f2bf(W2[k * 64 + n]);
    }
}

// ---------------- k1: fused node linears (q,k,v,skip), fp32 VALU ----------------
#define NPB 8
__global__ __launch_bounds__(256) void k1_node_linear(
    const float* __restrict__ x,
    const float* __restrict__ Wq, const float* __restrict__ bq,
    const float* __restrict__ Wk, const float* __restrict__ bk,
    const float* __restrict__ Wv, const float* __restrict__ bv,
    const float* __restrict__ Ws, const float* __restrict__ bs,
    bf16* __restrict__ qo, bf16* __restrict__ ko, bf16* __restrict__ vo,
    float* __restrict__ skipf)
{
    __shared__ float xs[NPB][D_NODE];
    const int tid = threadIdx.x;
    const int n0 = blockIdx.x * NPB;
    for (int nn = 0; nn < NPB; ++nn) {
        const int n = n0 + nn;
        xs[nn][tid] = (n < N_NODES) ? x[(size_t)n * D_NODE + tid] : 0.f;
    }
    __syncthreads();
    const int j = tid;
    float aq[NPB], ak[NPB], av[NPB], as_[NPB];
    const float bqv = bq[j], bkv = bk[j], bvv = bv[j], bsv = bs[j];
    #pragma unroll
    for (int nn = 0; nn < NPB; ++nn) { aq[nn]=bqv; ak[nn]=bkv; av[nn]=bvv; as_[nn]=bsv; }
    #pragma unroll 2
    for (int i = 0; i < D_NODE; ++i) {
        const float wq = Wq[i * D_NODE + j];
        const float wk = Wk[i * D_NODE + j];
        const float wv = Wv[i * D_NODE + j];
        const float ws = Ws[i * D_NODE + j];
        #pragma unroll
        for (int nn = 0; nn < NPB; ++nn) {
            const float xv = xs[nn][i];
            aq[nn]  = fmaf(xv, wq, aq[nn]);
            ak[nn]  = fmaf(xv, wk, ak[nn]);
            av[nn]  = fmaf(xv, wv, av[nn]);
            as_[nn] = fmaf(xv, ws, as_[nn]);
        }
    }
    for (int nn = 0; nn < NPB; ++nn) {
        const int n = n0 + nn;
        if (n < N_NODES) {
            qo[(size_t)n * D_NODE + j] = f2bf(aq[nn]);
            ko[(size_t)n * D_NODE + j] = f2bf(ak[nn]);
            vo[(size_t)n * D_NODE + j] = f2bf(av[nn]);
            skipf[(size_t)n * D_NODE + j] = as_[nn];
        }
    }
}

// ---------------- k2: MFMA eproj + attention scatter ----------------
#define EA_LD 72
#define WET_LD 72
#define EP_LD 264
__global__ __launch_bounds__(256) void k2_attn(
    const int* __restrict__ esrc, const int* __restrict__ edst,
    const float* __restrict__ ea, const bf16* __restrict__ WeT,
    const bf16* __restrict__ q, const bf16* __restrict__ k, const bf16* __restrict__ v,
    float* __restrict__ msg, float* __restrict__ denom)
{
    __shared__ unsigned short ea_s[64 * EA_LD];
    __shared__ unsigned short wet_s[256 * WET_LD];
    __shared__ unsigned short ep_s[64 * EP_LD];
    const int tid = threadIdx.x;
    const int e0 = blockIdx.x * 64;

    { // stage ea tile (fp32 -> bf16): 4 threads/edge, 16 elems each
        const int e = tid >> 2, t = tid & 3;
        const float* src = ea + (size_t)(e0 + e) * 64 + t * 16;
        unsigned short tmp[16];
        #pragma unroll
        for (int u = 0; u < 16; ++u) tmp[u] = rawbf(src[u]);
        *(short8b*)&ea_s[e * EA_LD + t * 16]     = *(short8b*)&tmp[0];
        *(short8b*)&ea_s[e * EA_LD + t * 16 + 8] = *(short8b*)&tmp[8];
    }
    { // stage WeT (bf16): one 64-elem row per thread
        const short8b* src = (const short8b*)(WeT + (size_t)tid * 64);
        #pragma unroll
        for (int u = 0; u < 8; ++u)
            *(short8b*)&wet_s[tid * WET_LD + u * 8] = src[u];
    }
    __syncthreads();

    const int w = tid >> 6, l = tid & 63;
    const int row = l & 15, kg = l >> 4;

    { // eproj MFMA: wave w owns edges w*16..+15; K=64, N=256 (16 coltiles)
        short8b af0 = *(const short8b*)&ea_s[(w * 16 + row) * EA_LD + kg * 8];
        short8b af1 = *(const short8b*)&ea_s[(w * 16 + row) * EA_LD + 32 + kg * 8];
        #pragma unroll
        for (int ct = 0; ct < 16; ++ct) {
            f32x4 acc = {0.f, 0.f, 0.f, 0.f};
            short8b b0 = *(const short8b*)&wet_s[(ct * 16 + row) * WET_LD + kg * 8];
            short8b b1 = *(const short8b*)&wet_s[(ct * 16 + row) * WET_LD + 32 + kg * 8];
            acc = __builtin_amdgcn_mfma_f32_16x16x32_bf16(af0, b0, acc, 0, 0, 0);
            acc = __builtin_amdgcn_mfma_f32_16x16x32_bf16(af1, b1, acc, 0, 0, 0);
            #pragma unroll
            for (int r = 0; r < 4; ++r)   // D[row]=kg*4+r (edge), D[col]=ct*16+row
                ep_s[(w * 16 + kg * 4 + r) * EP_LD + ct * 16 + row] = rawbf(acc[r]);
        }
    }
    __syncthreads();

    // attention: wave w covers its 16 edges; lane covers channels j=l*4..l*4+3
    int sv = 0;
    if (l < 16)       sv = esrc[e0 + w * 16 + l];
    else if (l < 32)  sv = edst[e0 + w * 16 + (l - 16)];
    const float scale = 0.35355339059327373f;  // 1/sqrt(8)

    for (int i = 0; i < 16; ++i) {
        const int s = __shfl(sv, i);
        const int d = __shfl(sv, 16 + i);
        const ushort4v qv = *(const ushort4v*)(q + (size_t)d * 256 + l * 4);
        const ushort4v kv = *(const ushort4v*)(k + (size_t)s * 256 + l * 4);
        const ushort4v vv = *(const ushort4v*)(v + (size_t)s * 256 + l * 4);
        const ushort4v ep = *(const ushort4v*)&ep_s[(w * 16 + i) * EP_LD + l * 4];
        float p = 0.f, m[4];
        #pragma unroll
        for (int t = 0; t < 4; ++t) {
            const float epf = bfraw(ep[t]);
            p = fmaf(bfraw(qv[t]), bfraw(kv[t]) + epf, p);
            m[t] = bfraw(vv[t]) + epf;
        }
        p += __shfl_xor(p, 1);                 // head = l>>1 (2 lanes/head)
        const float ex = __expf(p * scale);
        if ((l & 1) == 0) atomicAdd(&denom[(size_t)d * HEADS + (l >> 1)], ex);
        #pragma unroll
        for (int t = 0; t < 4; ++t)
            atomicAdd(&msg[(size_t)d * 256 + l * 4 + t], m[t] * ex);
    }
}

// ---------------- k3: node finalize ----------------
__global__ __launch_bounds__(256) void k3_node_final(
    const float* __restrict__ msg, const float* __restrict__ denom,
    const float* __restrict__ skipf, float* __restrict__ out_x,
    bf16* __restrict__ xnb)
{
    const int t = blockIdx.x * 256 + threadIdx.x;    // 3.2M threads, 4 elems each
    const size_t j0 = (size_t)t * 4;
    const int n = (int)(j0 >> 8);
    const int h = ((int)(j0 & 255)) >> 3;
    const float dnm = denom[(size_t)n * HEADS + h] + 1e-16f;
    const f32x4 mv = *(const f32x4*)(msg + j0);
    const f32x4 sk = *(const f32x4*)(skipf + j0);
    f32x4 o; ushort4v ob;
    #pragma unroll
    for (int u = 0; u < 4; ++u) {
        const float xn = leaky(mv[u] / dnm + sk[u]);
        o[u] = xn; ob[u] = rawbf(xn);
    }
    *(f32x4*)(out_x + j0) = o;
    *(ushort4v*)(xnb + j0) = ob;
}

// ---------------- k4: edge MLP via MFMA ----------------
#define H_LD 584
__global__ __launch_bounds__(256) void k4_edge_mlp(
    const int* __restrict__ esrc, const int* __restrict__ edst,
    const bf16* __restrict__ xnb, const float* __restrict__ ea,
    const bf16* __restrict__ W1Tp, const float* __restrict__ b1,
    const bf16* __restrict__ W2T, const float* __restrict__ b2,
    float* __restrict__ out_e)
{
    __shared__ unsigned short h_s[64 * H_LD];   // 74752 B
    const int tid = threadIdx.x;
    const int e0 = blockIdx.x * 64;

    { // stage h = [ea | x_s | x_d]: 4 threads/edge
        const int e = tid >> 2, t = tid & 3;
        const int eg = e0 + e;
        const int s = esrc[eg], d = edst[eg];
        const float* pe = ea + (size_t)eg * 64 + t * 16;
        unsigned short tmp[16];
        #pragma unroll
        for (int u = 0; u < 16; ++u) tmp[u] = rawbf(pe[u]);
        *(short8b*)&h_s[e * H_LD + t * 16]     = *(short8b*)&tmp[0];
        *(short8b*)&h_s[e * H_LD + t * 16 + 8] = *(short8b*)&tmp[8];
        const short8b* ps = (const short8b*)(xnb + (size_t)s * 256 + t * 64);
        const short8b* pd = (const short8b*)(xnb + (size_t)d * 256 + t * 64);
        #pragma unroll
        for (int u = 0; u < 8; ++u) {
            *(short8b*)&h_s[e * H_LD + 64  + t * 64 + u * 8] = ps[u];
            *(short8b*)&h_s[e * H_LD + 320 + t * 64 + u * 8] = pd[u];
        }
    }
    __syncthreads();

    const int w = tid >> 6, l = tid & 63;
    const int row = l & 15, kg = l >> 4;

    // GEMM1: [16 x 576] @ W1 -> [16 x 64]; acc init = b1
    f32x4 acc[4];
    #pragma unroll
    for (int ct = 0; ct < 4; ++ct) {
        const float bv = b1[ct * 16 + row];
        acc[ct] = (f32x4){bv, bv, bv, bv};
    }
    for (int kc = 0; kc < 18; ++kc) {
        const short8b af = *(const short8b*)&h_s[(w * 16 + row) * H_LD + kc * 32 + kg * 8];
        #pragma unroll
        for (int ct = 0; ct < 4; ++ct) {
            const short8b bfr = *(const short8b*)(W1Tp + (size_t)(ct * 16 + row) * 576 + kc * 32 + kg * 8);
            acc[ct] = __builtin_amdgcn_mfma_f32_16x16x32_bf16(af, bfr, acc[ct], 0, 0, 0);
        }
    }
    // ea residual (C layout rows) from LDS before h2 overwrites it
    float ear[4][4];
    #pragma unroll
    for (int ct = 0; ct < 4; ++ct)
        #pragma unroll
        for (int r = 0; r < 4; ++r)
            ear[ct][r] = bfraw(h_s[(w * 16 + kg * 4 + r) * H_LD + ct * 16 + row]);
    __syncthreads();   // all GEMM1 LDS reads done before h2 overwrites h

    // h2 = leaky(acc) -> per-wave [16][72] region
    unsigned short* h2 = &h_s[w * 1152];
    #pragma unroll
    for (int ct = 0; ct < 4; ++ct)
        #pragma unroll
        for (int r = 0; r < 4; ++r)
            h2[(kg * 4 + r) * 72 + ct * 16 + row] = rawbf(leaky(acc[ct][r]));
    // same-wave LDS ops are in-order: no barrier before same-wave GEMM2 reads

    // GEMM2: [16 x 64] @ W2 -> [16 x 64]; acc init = b2
    f32x4 a2[4];
    #pragma unroll
    for (int ct = 0; ct < 4; ++ct) {
        const float bv = b2[ct * 16 + row];
        a2[ct] = (f32x4){bv, bv, bv, bv};
    }
    #pragma unroll
    for (int kc = 0; kc < 2; ++kc) {
        const short8b af = *(const short8b*)&h2[row * 72 + kc * 32 + kg * 8];
        #pragma unroll
        for (int ct = 0; ct < 4; ++ct) {
            const short8b bfr = *(const short8b*)(W2T + (size_t)(ct * 16 + row) * 64 + kc * 32 + kg * 8);
            a2[ct] = __builtin_amdgcn_mfma_f32_16x16x32_bf16(af, bfr, a2[ct], 0, 0, 0);
        }
    }
    // epilogue: out = leaky(ea + h2@W2+b2), fp32
    #pragma unroll
    for (int ct = 0; ct < 4; ++ct)
        #pragma unroll
        for (int r = 0; r < 4; ++r) {
            const int eg = e0 + w * 16 + kg * 4 + r;
            out_e[(size_t)eg * 64 + ct * 16 + row] = leaky(ear[ct][r] + a2[ct][r]);
        }
}

extern "C" void kernel_launch(void* const* d_in, const int* in_sizes, int n_in,
                              void* d_out, int out_size, void* d_ws, size_t ws_size,
                              hipStream_t stream)
{
    const float* x  = (const float*)d_in[0];
    const int*   ei = (const int*)d_in[1];
    const float* ea = (const float*)d_in[2];
    const float* Wq = (const float*)d_in[3];
    const float* bq = (const float*)d_in[4];
    const float* Wk = (const float*)d_in[5];
    const float* bk = (const float*)d_in[6];
    const float* Wv = (const float*)d_in[7];
    const float* bv = (const float*)d_in[8];
    const float* We = (const float*)d_in[9];
    const float* Ws = (const float*)d_in[10];
    const float* bs = (const float*)d_in[11];
    const float* W1 = (const float*)d_in[12];
    const float* b1 = (const float*)d_in[13];
    const float* W2 = (const float*)d_in[14];
    const float* b2 = (const float*)d_in[15];

    char* ws = (char*)d_ws;
    int*   flags = (int*)ws;
    int*   es32  = (int*)(ws + 4096);
    int*   ed32  = (int*)(ws + 1604096);
    bf16*  WeT   = (bf16*)(ws + 3400000);
    bf16*  W1Tp  = (bf16*)(ws + 3500000);
    bf16*  W2T   = (bf16*)(ws + 3600000);
    bf16*  qb    = (bf16*)(ws + 4000000);    // reused as xnb after k2
    bf16*  kb    = (bf16*)(ws + 29600000);
    bf16*  vb    = (bf16*)(ws + 55200000);
    float* msg   = (float*)(ws + 80800000);
    float* denom = (float*)(ws + 132000000);

    float* out_x = (float*)d_out;
    float* out_e = out_x + (size_t)N_NODES * D_NODE;
    float* skipf = out_e;   // skip staged in edge-out region; k4 overwrites last

    hipMemsetAsync(ws + 80800000, 0, 57600000, stream);   // msg + denom

    k0_detect<<<1, 64, 0, stream>>>(ei, flags);
    k0b_edges<<<(N_EDGES + 255) / 256, 256, 0, stream>>>(ei, flags, es32, ed32);
    kT_transpose<<<1, 256, 0, stream>>>(We, W1, W2, WeT, W1Tp, W2T);

    k1_node_linear<<<(N_NODES + NPB - 1) / NPB, 256, 0, stream>>>(
        x, Wq, bq, Wk, bk, Wv, bv, Ws, bs, qb, kb, vb, skipf);

    k2_attn<<<N_EDGES / 64, 256, 0, stream>>>(es32, ed32, ea, WeT, qb, kb, vb, msg, denom);

    k3_node_final<<<(N_NODES * D_NODE) / (256 * 4), 256, 0, stream>>>(
        msg, denom, skipf, out_x, qb);

    k4_edge_mlp<<<N_EDGES / 64, 256, 0, stream>>>(es32, ed32, qb, ea, W1Tp, b1, W2T, b2, out_e);
}

// Round 5
// 1154.640 us; speedup vs baseline: 1.9061x; 1.9061x over previous
//
#include <hip/hip_runtime.h>
#include <hip/hip_bf16.h>

// GCNBlock: TransformerConv(32 heads, dim 8, edge_dim 64) + EdgeResidualLayer
// N=50000, E=400000, D_NODE=256, D_EDGE=64. FP32 in/out, int64 edge_index.
// Internals: bf16 MFMA (16x16x32) with fp32 accumulate.
//
// Round 5: kill the atomic-RMW wall (k2 was 1432us at VALUBusy 2.9%,
// WRITE_SIZE 1.65GB). Edges are dst-sorted on device (CSR scatter); k2
// accumulates per-dst runs in registers and flushes ~1 atomic set per run
// (mean degree 8). k1 moves to MFMA. k4 consumes sorted order too.
//
//  k0   : index width flag
//  kcd/kcs/kct: degree count -> exclusive scan -> scatter (ssort,dsort,eidsort)
//  kT   : WeT, W1Tp (perm), W2T, WT4 (q,k,v,s) bf16 transposes
//  k1   : q,k,v (bf16 ws) + skip (fp32, staged in out_e region) via MFMA
//  k2   : per 64-sorted-edge tile: eproj=ea@We MFMA -> LDS; run-compressed
//         attention scatter (softmax normalization commutes with segment sum)
//  k3   : x_new = leaky(msg/denom + skip) -> out_x fp32 + bf16 copy (xnb)
//  k4   : edge MLP, 2 MFMA GEMMs on [ea|x_s|x_d], sorted tiles, scatter out

#define N_NODES 50000
#define N_EDGES 400000
#define D_NODE 256
#define D_EDGE 64
#define HEADS 32
#define LRELU 0.01f

typedef __hip_bfloat16 bf16;
typedef __attribute__((ext_vector_type(8))) short short8b;          // 8 bf16
typedef __attribute__((ext_vector_type(4))) float f32x4;
typedef __attribute__((ext_vector_type(4))) unsigned short ushort4v;

__device__ __forceinline__ float bf2f(bf16 v) { return __bfloat162float(v); }
__device__ __forceinline__ bf16 f2bf(float f) { return __float2bfloat16(f); }
__device__ __forceinline__ float bfraw(unsigned short u) {
    return __uint_as_float(((unsigned int)u) << 16);
}
__device__ __forceinline__ unsigned short rawbf(float f) {
    bf16 t = f2bf(f); return *(unsigned short*)&t;
}
__device__ __forceinline__ float leaky(float v) { return v >= 0.f ? v : LRELU * v; }

// ---------------- k0: index width detection (1 wave) ----------------
__global__ void k0_detect(const int* __restrict__ ei, int* __restrict__ flags)
{
    const int lane = threadIdx.x;
    const unsigned long long mz = __ballot(ei[2 * lane + 1] == 0);
    if (lane == 0) flags[0] = (__popcll(mz) >= 48) ? 1 : 0;   // 1 => int64
}

__device__ __forceinline__ void load_edge(const int* ei, int f, int i, int& s, int& d)
{
    if (f) {
        const long long* e64 = (const long long*)ei;
        s = (int)e64[i]; d = (int)e64[N_EDGES + i];
    } else {
        s = ei[i]; d = ei[N_EDGES + i];
    }
}

// ---------------- CSR build ----------------
__global__ __launch_bounds__(256) void kcd_degree(
    const int* __restrict__ ei, const int* __restrict__ flags, int* __restrict__ deg)
{
    const int i = blockIdx.x * 256 + threadIdx.x;
    if (i >= N_EDGES) return;
    int s, d; load_edge(ei, flags[0], i, s, d);
    atomicAdd(&deg[d], 1);
}

__global__ __launch_bounds__(1024) void kcs_scan(int* __restrict__ cur)  // deg -> excl. offsets
{
    __shared__ int ps[1024];
    const int t = threadIdx.x;
    const int CH = (N_NODES + 1023) / 1024;   // 49
    const int base = t * CH;
    int sum = 0;
    for (int i = 0; i < CH; ++i) {
        const int n = base + i;
        if (n < N_NODES) sum += cur[n];
    }
    ps[t] = sum;
    __syncthreads();
    for (int off = 1; off < 1024; off <<= 1) {
        const int v = (t >= off) ? ps[t - off] : 0;
        __syncthreads();
        ps[t] += v;
        __syncthreads();
    }
    int excl = (t == 0) ? 0 : ps[t - 1];
    for (int i = 0; i < CH; ++i) {
        const int n = base + i;
        if (n < N_NODES) {
            const int d = cur[n];
            cur[n] = excl;
            excl += d;
        }
    }
}

__global__ __launch_bounds__(256) void kct_scatter(
    const int* __restrict__ ei, const int* __restrict__ flags, int* __restrict__ cursor,
    int* __restrict__ ssort, int* __restrict__ dsort, int* __restrict__ eidsort)
{
    const int i = blockIdx.x * 256 + threadIdx.x;
    if (i >= N_EDGES) return;
    int s, d; load_edge(ei, flags[0], i, s, d);
    const int pos = atomicAdd(&cursor[d], 1);
    ssort[pos] = s; dsort[pos] = d; eidsort[pos] = i;
}

// ---------------- kT: weight transposes (fp32 -> bf16) ----------------
// WeT[n][k]=We[k][n]; W1Tp[n][k']=W1[perm(k')][n], perm(k')=k'<64?512+k':k'-64;
// W2T[n][k]=W2[k][n]; WT4[m][n][k]=Wm[k][n] for m in {q,k,v,s}
__global__ __launch_bounds__(256) void kT_transpose(
    const float* __restrict__ We, const float* __restrict__ W1, const float* __restrict__ W2,
    const float* __restrict__ Wq, const float* __restrict__ Wk,
    const float* __restrict__ Wv, const float* __restrict__ Ws,
    bf16* __restrict__ WeT, bf16* __restrict__ W1Tp, bf16* __restrict__ W2T,
    bf16* __restrict__ WT4)
{
    const int gid = blockIdx.x * 256 + threadIdx.x;
    const int gsz = gridDim.x * 256;
    for (int i = gid; i < 256 * 64; i += gsz) {
        const int n = i >> 6, k = i & 63;
        WeT[i] = f2bf(We[k * 256 + n]);
    }
    for (int i = gid; i < 64 * 576; i += gsz) {
        const int n = i / 576, kp = i % 576;
        const int k = (kp < 64) ? (512 + kp) : (kp - 64);
        W1Tp[i] = f2bf(W1[k * 64 + n]);
    }
    for (int i = gid; i < 64 * 64; i += gsz) {
        const int n = i >> 6, k = i & 63;
        W2T[i] = f2bf(W2[k * 64 + n]);
    }
    for (int i = gid; i < 4 * 256 * 256; i += gsz) {
        const int m = i >> 16, rem = i & 65535;
        const int n = rem >> 8, kk = rem & 255;
        const float* W = (m == 0) ? Wq : (m == 1) ? Wk : (m == 2) ? Wv : Ws;
        WT4[i] = f2bf(W[kk * 256 + n]);
    }
}

// ---------------- k1: node linears via MFMA ----------------
#define X_LD 264
__global__ __launch_bounds__(256) void k1_node_mfma(
    const float* __restrict__ x, const bf16* __restrict__ WT4,
    const float* __restrict__ bq, const float* __restrict__ bk,
    const float* __restrict__ bv, const float* __restrict__ bs,
    bf16* __restrict__ qo, bf16* __restrict__ ko, bf16* __restrict__ vo,
    float* __restrict__ skipf)
{
    __shared__ unsigned short xs[64 * X_LD];   // 33792 B
    const int tid = threadIdx.x;
    const int n0 = blockIdx.x * 64;
    { // stage x tile (fp32 -> bf16): 4 threads/node, 64 elems each
        const int e = tid >> 2, t = tid & 3;
        const int n = n0 + e;
        const float* src = x + (size_t)n * 256 + t * 64;
        for (int c = 0; c < 4; ++c) {
            unsigned short tmp[16];
            #pragma unroll
            for (int u = 0; u < 16; ++u)
                tmp[u] = (n < N_NODES) ? rawbf(src[c * 16 + u]) : 0;
            *(short8b*)&xs[e * X_LD + t * 64 + c * 16]     = *(short8b*)&tmp[0];
            *(short8b*)&xs[e * X_LD + t * 64 + c * 16 + 8] = *(short8b*)&tmp[8];
        }
    }
    __syncthreads();

    const int w = tid >> 6, l = tid & 63;
    const int row = l & 15, kg = l >> 4;
    short8b af[8];
    #pragma unroll
    for (int kc = 0; kc < 8; ++kc)
        af[kc] = *(const short8b*)&xs[(w * 16 + row) * X_LD + kc * 32 + kg * 8];

    #pragma unroll
    for (int m = 0; m < 4; ++m) {
        const bf16* WT = WT4 + (size_t)m * 65536;
        const float* bias = (m == 0) ? bq : (m == 1) ? bk : (m == 2) ? bv : bs;
        #pragma unroll 4
        for (int ct = 0; ct < 16; ++ct) {
            const float bvv = bias[ct * 16 + row];
            f32x4 acc = {bvv, bvv, bvv, bvv};
            #pragma unroll
            for (int kc = 0; kc < 8; ++kc) {
                const short8b bfr = *(const short8b*)(WT + (size_t)(ct * 16 + row) * 256 + kc * 32 + kg * 8);
                acc = __builtin_amdgcn_mfma_f32_16x16x32_bf16(af[kc], bfr, acc, 0, 0, 0);
            }
            const int col = ct * 16 + row;
            #pragma unroll
            for (int r = 0; r < 4; ++r) {
                const int n = n0 + w * 16 + kg * 4 + r;
                if (n < N_NODES) {
                    if (m == 0)      qo[(size_t)n * 256 + col] = f2bf(acc[r]);
                    else if (m == 1) ko[(size_t)n * 256 + col] = f2bf(acc[r]);
                    else if (m == 2) vo[(size_t)n * 256 + col] = f2bf(acc[r]);
                    else             skipf[(size_t)n * 256 + col] = acc[r];
                }
            }
        }
    }
}

// ---------------- k2: MFMA eproj + run-compressed attention scatter ----------------
#define EA_LD 72
#define EP_LD 264
__global__ __launch_bounds__(256) void k2_attn(
    const int* __restrict__ ssort, const int* __restrict__ dsort,
    const int* __restrict__ eidsort,
    const float* __restrict__ ea, const bf16* __restrict__ WeT,
    const bf16* __restrict__ q, const bf16* __restrict__ k, const bf16* __restrict__ v,
    float* __restrict__ msg, float* __restrict__ denom)
{
    __shared__ unsigned short ea_s[64 * EA_LD];   // 9216 B
    __shared__ unsigned short ep_s[64 * EP_LD];   // 33792 B  (total 43 KB -> 3 blk/CU)
    const int tid = threadIdx.x;
    const int e0 = blockIdx.x * 64;

    { // stage ea tile via sorted ids (fp32 -> bf16): 4 threads/edge
        const int e = tid >> 2, t = tid & 3;
        const int eg = eidsort[e0 + e];
        const float* src = ea + (size_t)eg * 64 + t * 16;
        unsigned short tmp[16];
        #pragma unroll
        for (int u = 0; u < 16; ++u) tmp[u] = rawbf(src[u]);
        *(short8b*)&ea_s[e * EA_LD + t * 16]     = *(short8b*)&tmp[0];
        *(short8b*)&ea_s[e * EA_LD + t * 16 + 8] = *(short8b*)&tmp[8];
    }
    __syncthreads();

    const int w = tid >> 6, l = tid & 63;
    const int row = l & 15, kg = l >> 4;

    { // eproj MFMA: wave w owns sorted edges w*16..+15; B straight from L1/L2
        const short8b af0 = *(const short8b*)&ea_s[(w * 16 + row) * EA_LD + kg * 8];
        const short8b af1 = *(const short8b*)&ea_s[(w * 16 + row) * EA_LD + 32 + kg * 8];
        #pragma unroll 4
        for (int ct = 0; ct < 16; ++ct) {
            f32x4 acc = {0.f, 0.f, 0.f, 0.f};
            const short8b b0 = *(const short8b*)(WeT + (size_t)(ct * 16 + row) * 64 + kg * 8);
            const short8b b1 = *(const short8b*)(WeT + (size_t)(ct * 16 + row) * 64 + 32 + kg * 8);
            acc = __builtin_amdgcn_mfma_f32_16x16x32_bf16(af0, b0, acc, 0, 0, 0);
            acc = __builtin_amdgcn_mfma_f32_16x16x32_bf16(af1, b1, acc, 0, 0, 0);
            #pragma unroll
            for (int r = 0; r < 4; ++r)
                ep_s[(w * 16 + kg * 4 + r) * EP_LD + ct * 16 + row] = rawbf(acc[r]);
        }
    }
    __syncthreads();

    // attention: lane covers channels j=l*4..l*4+3; runs of equal dst are
    // register-accumulated and flushed once (edges are dst-sorted).
    int sv = 0;
    if (l < 16)      sv = ssort[e0 + w * 16 + l];
    else if (l < 32) sv = dsort[e0 + w * 16 + (l - 16)];
    const float scale = 0.35355339059327373f;   // 1/sqrt(8)

    float macc[4] = {0.f, 0.f, 0.f, 0.f};
    float dacc = 0.f;
    int dprev = -1;
    ushort4v qv = {0, 0, 0, 0};

    for (int i = 0; i < 16; ++i) {
        const int s = __shfl(sv, i);
        const int d = __shfl(sv, 16 + i);
        if (d != dprev) {                      // wave-uniform branch
            if (dprev >= 0) {
                #pragma unroll
                for (int t = 0; t < 4; ++t)
                    atomicAdd(&msg[(size_t)dprev * 256 + l * 4 + t], macc[t]);
                if ((l & 1) == 0)
                    atomicAdd(&denom[(size_t)dprev * HEADS + (l >> 1)], dacc);
                macc[0] = macc[1] = macc[2] = macc[3] = 0.f;
                dacc = 0.f;
            }
            qv = *(const ushort4v*)(q + (size_t)d * 256 + l * 4);
            dprev = d;
        }
        const ushort4v kv = *(const ushort4v*)(k + (size_t)s * 256 + l * 4);
        const ushort4v vv = *(const ushort4v*)(v + (size_t)s * 256 + l * 4);
        const ushort4v ep = *(const ushort4v*)&ep_s[(w * 16 + i) * EP_LD + l * 4];
        float p = 0.f, m4[4];
        #pragma unroll
        for (int t = 0; t < 4; ++t) {
            const float epf = bfraw(ep[t]);
            p = fmaf(bfraw(qv[t]), bfraw(kv[t]) + epf, p);
            m4[t] = bfraw(vv[t]) + epf;
        }
        p += __shfl_xor(p, 1);                 // head = l>>1 (2 lanes/head)
        const float ex = __expf(p * scale);
        #pragma unroll
        for (int t = 0; t < 4; ++t) macc[t] = fmaf(m4[t], ex, macc[t]);
        dacc += ex;
    }
    #pragma unroll
    for (int t = 0; t < 4; ++t)
        atomicAdd(&msg[(size_t)dprev * 256 + l * 4 + t], macc[t]);
    if ((l & 1) == 0)
        atomicAdd(&denom[(size_t)dprev * HEADS + (l >> 1)], dacc);
}

// ---------------- k3: node finalize ----------------
__global__ __launch_bounds__(256) void k3_node_final(
    const float* __restrict__ msg, const float* __restrict__ denom,
    const float* __restrict__ skipf, float* __restrict__ out_x,
    bf16* __restrict__ xnb)
{
    const int t = blockIdx.x * 256 + threadIdx.x;
    const size_t j0 = (size_t)t * 4;
    const int n = (int)(j0 >> 8);
    const int h = ((int)(j0 & 255)) >> 3;
    const float dnm = denom[(size_t)n * HEADS + h] + 1e-16f;
    const f32x4 mv = *(const f32x4*)(msg + j0);
    const f32x4 sk = *(const f32x4*)(skipf + j0);
    f32x4 o; ushort4v ob;
    #pragma unroll
    for (int u = 0; u < 4; ++u) {
        const float xn = leaky(mv[u] / dnm + sk[u]);
        o[u] = xn; ob[u] = rawbf(xn);
    }
    *(f32x4*)(out_x + j0) = o;
    *(ushort4v*)(xnb + j0) = ob;
}

// ---------------- k4: edge MLP via MFMA (sorted tiles) ----------------
#define H_LD 584
__global__ __launch_bounds__(256) void k4_edge_mlp(
    const int* __restrict__ ssort, const int* __restrict__ dsort,
    const int* __restrict__ eidsort,
    const bf16* __restrict__ xnb, const float* __restrict__ ea,
    const bf16* __restrict__ W1Tp, const float* __restrict__ b1,
    const bf16* __restrict__ W2T, const float* __restrict__ b2,
    float* __restrict__ out_e)
{
    __shared__ unsigned short h_s[64 * H_LD];   // 74752 B
    const int tid = threadIdx.x;
    const int e0 = blockIdx.x * 64;

    { // stage h = [ea | x_s | x_d]: 4 threads/edge
        const int e = tid >> 2, t = tid & 3;
        const int sl = e0 + e;
        const int eg = eidsort[sl];
        const int s = ssort[sl], d = dsort[sl];
        const float* pe = ea + (size_t)eg * 64 + t * 16;
        unsigned short tmp[16];
        #pragma unroll
        for (int u = 0; u < 16; ++u) tmp[u] = rawbf(pe[u]);
        *(short8b*)&h_s[e * H_LD + t * 16]     = *(short8b*)&tmp[0];
        *(short8b*)&h_s[e * H_LD + t * 16 + 8] = *(short8b*)&tmp[8];
        const short8b* ps = (const short8b*)(xnb + (size_t)s * 256 + t * 64);
        const short8b* pd = (const short8b*)(xnb + (size_t)d * 256 + t * 64);
        #pragma unroll
        for (int u = 0; u < 8; ++u) {
            *(short8b*)&h_s[e * H_LD + 64  + t * 64 + u * 8] = ps[u];
            *(short8b*)&h_s[e * H_LD + 320 + t * 64 + u * 8] = pd[u];
        }
    }
    __syncthreads();

    const int w = tid >> 6, l = tid & 63;
    const int row = l & 15, kg = l >> 4;

    // GEMM1: [16 x 576] @ W1 -> [16 x 64]; acc init = b1
    f32x4 acc[4];
    #pragma unroll
    for (int ct = 0; ct < 4; ++ct) {
        const float bvv = b1[ct * 16 + row];
        acc[ct] = (f32x4){bvv, bvv, bvv, bvv};
    }
    for (int kc = 0; kc < 18; ++kc) {
        const short8b af = *(const short8b*)&h_s[(w * 16 + row) * H_LD + kc * 32 + kg * 8];
        #pragma unroll
        for (int ct = 0; ct < 4; ++ct) {
            const short8b bfr = *(const short8b*)(W1Tp + (size_t)(ct * 16 + row) * 576 + kc * 32 + kg * 8);
            acc[ct] = __builtin_amdgcn_mfma_f32_16x16x32_bf16(af, bfr, acc[ct], 0, 0, 0);
        }
    }
    // ea residual (C layout rows) from LDS before h2 overwrites it
    float ear[4][4];
    #pragma unroll
    for (int ct = 0; ct < 4; ++ct)
        #pragma unroll
        for (int r = 0; r < 4; ++r)
            ear[ct][r] = bfraw(h_s[(w * 16 + kg * 4 + r) * H_LD + ct * 16 + row]);
    __syncthreads();   // all GEMM1 LDS reads done before h2 overwrites h

    // h2 = leaky(acc) -> per-wave [16][72] region
    unsigned short* h2 = &h_s[w * 1152];
    #pragma unroll
    for (int ct = 0; ct < 4; ++ct)
        #pragma unroll
        for (int r = 0; r < 4; ++r)
            h2[(kg * 4 + r) * 72 + ct * 16 + row] = rawbf(leaky(acc[ct][r]));
    // same-wave LDS ops are in-order: no barrier before same-wave reads

    // GEMM2: [16 x 64] @ W2 -> [16 x 64]; acc init = b2
    f32x4 a2[4];
    #pragma unroll
    for (int ct = 0; ct < 4; ++ct) {
        const float bvv = b2[ct * 16 + row];
        a2[ct] = (f32x4){bvv, bvv, bvv, bvv};
    }
    #pragma unroll
    for (int kc = 0; kc < 2; ++kc) {
        const short8b af = *(const short8b*)&h2[row * 72 + kc * 32 + kg * 8];
        #pragma unroll
        for (int ct = 0; ct < 4; ++ct) {
            const short8b bfr = *(const short8b*)(W2T + (size_t)(ct * 16 + row) * 64 + kc * 32 + kg * 8);
            a2[ct] = __builtin_amdgcn_mfma_f32_16x16x32_bf16(af, bfr, a2[ct], 0, 0, 0);
        }
    }
    // epilogue: out = leaky(ea + h2@W2+b2), scattered to original edge ids
    #pragma unroll
    for (int ct = 0; ct < 4; ++ct)
        #pragma unroll
        for (int r = 0; r < 4; ++r) {
            const int eg = eidsort[e0 + w * 16 + kg * 4 + r];
            out_e[(size_t)eg * 64 + ct * 16 + row] = leaky(ear[ct][r] + a2[ct][r]);
        }
}

extern "C" void kernel_launch(void* const* d_in, const int* in_sizes, int n_in,
                              void* d_out, int out_size, void* d_ws, size_t ws_size,
                              hipStream_t stream)
{
    const float* x  = (const float*)d_in[0];
    const int*   ei = (const int*)d_in[1];
    const float* ea = (const float*)d_in[2];
    const float* Wq = (const float*)d_in[3];
    const float* bq = (const float*)d_in[4];
    const float* Wk = (const float*)d_in[5];
    const float* bk = (const float*)d_in[6];
    const float* Wv = (const float*)d_in[7];
    const float* bv = (const float*)d_in[8];
    const float* We = (const float*)d_in[9];
    const float* Ws = (const float*)d_in[10];
    const float* bs = (const float*)d_in[11];
    const float* W1 = (const float*)d_in[12];
    const float* b1 = (const float*)d_in[13];
    const float* W2 = (const float*)d_in[14];
    const float* b2 = (const float*)d_in[15];

    char* ws = (char*)d_ws;
    int*   flags  = (int*)ws;                       // 4 KB
    int*   ssort  = (int*)(ws + 4096);              // 1.6 MB
    int*   dsort  = (int*)(ws + 1604096);           // 1.6 MB
    int*   eids   = (int*)(ws + 3204096);           // 1.6 MB
    int*   cursor = (int*)(ws + 4804096);           // 200 KB (deg -> offsets)
    bf16*  WeT    = (bf16*)(ws + 5004096);          // 32 KB
    bf16*  W1Tp   = (bf16*)(ws + 5036864);          // 72 KB
    bf16*  W2T    = (bf16*)(ws + 5110592);          // 8 KB
    bf16*  WT4    = (bf16*)(ws + 5118784);          // 512 KB
    bf16*  qb     = (bf16*)(ws + 5643072);          // 25.6 MB (xnb after k2)
    bf16*  kb     = (bf16*)(ws + 31243072);         // 25.6 MB
    bf16*  vb     = (bf16*)(ws + 56843072);         // 25.6 MB
    float* msg    = (float*)(ws + 82443072);        // 51.2 MB
    float* denom  = (float*)(ws + 133643072);       // 6.4 MB  (ends 140.0 MB)

    float* out_x = (float*)d_out;
    float* out_e = out_x + (size_t)N_NODES * D_NODE;
    float* skipf = out_e;   // skip staged in edge-out region; k4 overwrites last

    hipMemsetAsync(ws + 82443072, 0, 57600000, stream);   // msg + denom
    hipMemsetAsync(cursor, 0, N_NODES * 4, stream);       // degree counters

    k0_detect<<<1, 64, 0, stream>>>(ei, flags);
    kcd_degree<<<(N_EDGES + 255) / 256, 256, 0, stream>>>(ei, flags, cursor);
    kcs_scan<<<1, 1024, 0, stream>>>(cursor);
    kct_scatter<<<(N_EDGES + 255) / 256, 256, 0, stream>>>(ei, flags, cursor, ssort, dsort, eids);

    kT_transpose<<<64, 256, 0, stream>>>(We, W1, W2, Wq, Wk, Wv, Ws, WeT, W1Tp, W2T, WT4);

    k1_node_mfma<<<(N_NODES + 63) / 64, 256, 0, stream>>>(
        x, WT4, bq, bk, bv, bs, qb, kb, vb, skipf);

    k2_attn<<<N_EDGES / 64, 256, 0, stream>>>(ssort, dsort, eids, ea, WeT, qb, kb, vb, msg, denom);

    k3_node_final<<<(N_NODES * D_NODE) / (256 * 4), 256, 0, stream>>>(
        msg, denom, skipf, out_x, qb);

    k4_edge_mlp<<<N_EDGES / 64, 256, 0, stream>>>(
        ssort, dsort, eids, qb, ea, W1Tp, b1, W2T, b2, out_e);
}

// Round 6
// 1099.676 us; speedup vs baseline: 2.0014x; 1.0500x over previous
//
#include <hip/hip_runtime.h>
#include <hip/hip_bf16.h>

// GCNBlock: TransformerConv(32 heads, dim 8, edge_dim 64) + EdgeResidualLayer
// N=50000, E=400000, D_NODE=256, D_EDGE=64. FP32 in/out, int64 edge_index.
// Internals: bf16 MFMA (16x16x32) with fp32 accumulate.
//
// Round 6: fix k1's L2 weight-thrash (FETCH was 499MB vs 52MB ideal: x-read
// and output-write streams evicted the 512KB weight set from every XCD L2).
//  - k1: nontemporal x loads; per-m LDS-bounce of results -> fully coalesced
//        128B/thread nontemporal stores; skip stored bf16.
//  - k3: bf16 skip; nt loads of msg; nt store of out_x.
//  - k2/k4: f32x4 ea staging; k4 nt scattered stores.
// Everything else (CSR dst-sort, run-compressed atomic scatter, MFMA tiles)
// carried from round 5 (1155us, absmax 0.03125).

#define N_NODES 50000
#define N_EDGES 400000
#define D_NODE 256
#define D_EDGE 64
#define HEADS 32
#define LRELU 0.01f

typedef __hip_bfloat16 bf16;
typedef __attribute__((ext_vector_type(8))) short short8b;          // 8 bf16
typedef __attribute__((ext_vector_type(4))) float f32x4;
typedef __attribute__((ext_vector_type(4))) unsigned short ushort4v;

__device__ __forceinline__ float bf2f(bf16 v) { return __bfloat162float(v); }
__device__ __forceinline__ bf16 f2bf(float f) { return __float2bfloat16(f); }
__device__ __forceinline__ float bfraw(unsigned short u) {
    return __uint_as_float(((unsigned int)u) << 16);
}
__device__ __forceinline__ unsigned short rawbf(float f) {
    bf16 t = f2bf(f); return *(unsigned short*)&t;
}
__device__ __forceinline__ float leaky(float v) { return v >= 0.f ? v : LRELU * v; }

// ---------------- k0: index width detection (1 wave) ----------------
__global__ void k0_detect(const int* __restrict__ ei, int* __restrict__ flags)
{
    const int lane = threadIdx.x;
    const unsigned long long mz = __ballot(ei[2 * lane + 1] == 0);
    if (lane == 0) flags[0] = (__popcll(mz) >= 48) ? 1 : 0;   // 1 => int64
}

__device__ __forceinline__ void load_edge(const int* ei, int f, int i, int& s, int& d)
{
    if (f) {
        const long long* e64 = (const long long*)ei;
        s = (int)e64[i]; d = (int)e64[N_EDGES + i];
    } else {
        s = ei[i]; d = ei[N_EDGES + i];
    }
}

// ---------------- CSR build ----------------
__global__ __launch_bounds__(256) void kcd_degree(
    const int* __restrict__ ei, const int* __restrict__ flags, int* __restrict__ deg)
{
    const int i = blockIdx.x * 256 + threadIdx.x;
    if (i >= N_EDGES) return;
    int s, d; load_edge(ei, flags[0], i, s, d);
    atomicAdd(&deg[d], 1);
}

__global__ __launch_bounds__(1024) void kcs_scan(int* __restrict__ cur)  // deg -> excl. offsets
{
    __shared__ int ps[1024];
    const int t = threadIdx.x;
    const int CH = (N_NODES + 1023) / 1024;   // 49
    const int base = t * CH;
    int sum = 0;
    for (int i = 0; i < CH; ++i) {
        const int n = base + i;
        if (n < N_NODES) sum += cur[n];
    }
    ps[t] = sum;
    __syncthreads();
    for (int off = 1; off < 1024; off <<= 1) {
        const int v = (t >= off) ? ps[t - off] : 0;
        __syncthreads();
        ps[t] += v;
        __syncthreads();
    }
    int excl = (t == 0) ? 0 : ps[t - 1];
    for (int i = 0; i < CH; ++i) {
        const int n = base + i;
        if (n < N_NODES) {
            const int d = cur[n];
            cur[n] = excl;
            excl += d;
        }
    }
}

__global__ __launch_bounds__(256) void kct_scatter(
    const int* __restrict__ ei, const int* __restrict__ flags, int* __restrict__ cursor,
    int* __restrict__ ssort, int* __restrict__ dsort, int* __restrict__ eidsort)
{
    const int i = blockIdx.x * 256 + threadIdx.x;
    if (i >= N_EDGES) return;
    int s, d; load_edge(ei, flags[0], i, s, d);
    const int pos = atomicAdd(&cursor[d], 1);
    ssort[pos] = s; dsort[pos] = d; eidsort[pos] = i;
}

// ---------------- kT: weight transposes (fp32 -> bf16) ----------------
__global__ __launch_bounds__(256) void kT_transpose(
    const float* __restrict__ We, const float* __restrict__ W1, const float* __restrict__ W2,
    const float* __restrict__ Wq, const float* __restrict__ Wk,
    const float* __restrict__ Wv, const float* __restrict__ Ws,
    bf16* __restrict__ WeT, bf16* __restrict__ W1Tp, bf16* __restrict__ W2T,
    bf16* __restrict__ WT4)
{
    const int gid = blockIdx.x * 256 + threadIdx.x;
    const int gsz = gridDim.x * 256;
    for (int i = gid; i < 256 * 64; i += gsz) {
        const int n = i >> 6, k = i & 63;
        WeT[i] = f2bf(We[k * 256 + n]);
    }
    for (int i = gid; i < 64 * 576; i += gsz) {
        const int n = i / 576, kp = i % 576;
        const int k = (kp < 64) ? (512 + kp) : (kp - 64);
        W1Tp[i] = f2bf(W1[k * 64 + n]);
    }
    for (int i = gid; i < 64 * 64; i += gsz) {
        const int n = i >> 6, k = i & 63;
        W2T[i] = f2bf(W2[k * 64 + n]);
    }
    for (int i = gid; i < 4 * 256 * 256; i += gsz) {
        const int m = i >> 16, rem = i & 65535;
        const int n = rem >> 8, kk = rem & 255;
        const float* W = (m == 0) ? Wq : (m == 1) ? Wk : (m == 2) ? Wv : Ws;
        WT4[i] = f2bf(W[kk * 256 + n]);
    }
}

// ---------------- k1: node linears via MFMA (nt streams, LDS store-bounce) ----------------
#define X_LD 264
__global__ __launch_bounds__(256) void k1_node_mfma(
    const float* __restrict__ x, const bf16* __restrict__ WT4,
    const float* __restrict__ bq, const float* __restrict__ bk,
    const float* __restrict__ bv, const float* __restrict__ bs,
    bf16* __restrict__ qo, bf16* __restrict__ ko, bf16* __restrict__ vo,
    bf16* __restrict__ skipb)
{
    __shared__ unsigned short xs[64 * X_LD];   // 33792 B; reused as result bounce
    const int tid = threadIdx.x;
    const int n0 = blockIdx.x * 64;
    const int e = tid >> 2, t = tid & 3;       // node e, quarter t
    const int nmine = n0 + e;

    { // stage x tile (fp32 -> bf16), nontemporal f32x4 loads
        const f32x4* src = (const f32x4*)(x + (size_t)nmine * 256 + t * 64);
        #pragma unroll
        for (int c = 0; c < 4; ++c) {
            unsigned short tmp[16];
            if (nmine < N_NODES) {
                #pragma unroll
                for (int u = 0; u < 4; ++u) {
                    const f32x4 v = __builtin_nontemporal_load(src + c * 4 + u);
                    tmp[u * 4 + 0] = rawbf(v[0]); tmp[u * 4 + 1] = rawbf(v[1]);
                    tmp[u * 4 + 2] = rawbf(v[2]); tmp[u * 4 + 3] = rawbf(v[3]);
                }
            } else {
                #pragma unroll
                for (int u = 0; u < 16; ++u) tmp[u] = 0;
            }
            *(short8b*)&xs[e * X_LD + t * 64 + c * 16]     = *(short8b*)&tmp[0];
            *(short8b*)&xs[e * X_LD + t * 64 + c * 16 + 8] = *(short8b*)&tmp[8];
        }
    }
    __syncthreads();

    const int w = tid >> 6, l = tid & 63;
    const int row = l & 15, kg = l >> 4;
    short8b af[8];
    #pragma unroll
    for (int kc = 0; kc < 8; ++kc)
        af[kc] = *(const short8b*)&xs[(w * 16 + row) * X_LD + kc * 32 + kg * 8];

    for (int m = 0; m < 4; ++m) {
        const bf16* WT = WT4 + (size_t)m * 65536;
        const float* bias = (m == 0) ? bq : (m == 1) ? bk : (m == 2) ? bv : bs;
        __syncthreads();   // prior LDS reads (af / previous store phase) done
        #pragma unroll 4
        for (int ct = 0; ct < 16; ++ct) {
            const float bvv = bias[ct * 16 + row];
            f32x4 acc = {bvv, bvv, bvv, bvv};
            #pragma unroll
            for (int kc = 0; kc < 8; ++kc) {
                const short8b bfr = *(const short8b*)(WT + (size_t)(ct * 16 + row) * 256 + kc * 32 + kg * 8);
                acc = __builtin_amdgcn_mfma_f32_16x16x32_bf16(af[kc], bfr, acc, 0, 0, 0);
            }
            #pragma unroll
            for (int r = 0; r < 4; ++r)   // bounce: row = local node, col = output col
                xs[(w * 16 + kg * 4 + r) * X_LD + ct * 16 + row] = rawbf(acc[r]);
        }
        __syncthreads();
        if (nmine < N_NODES) {   // coalesced nt store: 128 B per thread
            bf16* dst = (m == 0) ? qo : (m == 1) ? ko : (m == 2) ? vo : skipb;
            short8b* dp = (short8b*)(dst + (size_t)nmine * 256 + t * 64);
            #pragma unroll
            for (int u = 0; u < 8; ++u)
                __builtin_nontemporal_store(
                    *(const short8b*)&xs[e * X_LD + t * 64 + u * 8], dp + u);
        }
    }
}

// ---------------- k2: MFMA eproj + run-compressed attention scatter ----------------
#define EA_LD 72
#define EP_LD 264
__global__ __launch_bounds__(256) void k2_attn(
    const int* __restrict__ ssort, const int* __restrict__ dsort,
    const int* __restrict__ eidsort,
    const float* __restrict__ ea, const bf16* __restrict__ WeT,
    const bf16* __restrict__ q, const bf16* __restrict__ k, const bf16* __restrict__ v,
    float* __restrict__ msg, float* __restrict__ denom)
{
    __shared__ unsigned short ea_s[64 * EA_LD];   // 9216 B
    __shared__ unsigned short ep_s[64 * EP_LD];   // 33792 B
    const int tid = threadIdx.x;
    const int e0 = blockIdx.x * 64;

    { // stage ea tile via sorted ids (fp32 -> bf16), f32x4 loads
        const int e = tid >> 2, t = tid & 3;
        const int eg = eidsort[e0 + e];
        const f32x4* src = (const f32x4*)(ea + (size_t)eg * 64 + t * 16);
        unsigned short tmp[16];
        #pragma unroll
        for (int u = 0; u < 4; ++u) {
            const f32x4 vv = src[u];
            tmp[u * 4 + 0] = rawbf(vv[0]); tmp[u * 4 + 1] = rawbf(vv[1]);
            tmp[u * 4 + 2] = rawbf(vv[2]); tmp[u * 4 + 3] = rawbf(vv[3]);
        }
        *(short8b*)&ea_s[e * EA_LD + t * 16]     = *(short8b*)&tmp[0];
        *(short8b*)&ea_s[e * EA_LD + t * 16 + 8] = *(short8b*)&tmp[8];
    }
    __syncthreads();

    const int w = tid >> 6, l = tid & 63;
    const int row = l & 15, kg = l >> 4;

    { // eproj MFMA
        const short8b af0 = *(const short8b*)&ea_s[(w * 16 + row) * EA_LD + kg * 8];
        const short8b af1 = *(const short8b*)&ea_s[(w * 16 + row) * EA_LD + 32 + kg * 8];
        #pragma unroll 4
        for (int ct = 0; ct < 16; ++ct) {
            f32x4 acc = {0.f, 0.f, 0.f, 0.f};
            const short8b b0 = *(const short8b*)(WeT + (size_t)(ct * 16 + row) * 64 + kg * 8);
            const short8b b1 = *(const short8b*)(WeT + (size_t)(ct * 16 + row) * 64 + 32 + kg * 8);
            acc = __builtin_amdgcn_mfma_f32_16x16x32_bf16(af0, b0, acc, 0, 0, 0);
            acc = __builtin_amdgcn_mfma_f32_16x16x32_bf16(af1, b1, acc, 0, 0, 0);
            #pragma unroll
            for (int r = 0; r < 4; ++r)
                ep_s[(w * 16 + kg * 4 + r) * EP_LD + ct * 16 + row] = rawbf(acc[r]);
        }
    }
    __syncthreads();

    // run-compressed attention scatter (edges dst-sorted)
    int sv = 0;
    if (l < 16)      sv = ssort[e0 + w * 16 + l];
    else if (l < 32) sv = dsort[e0 + w * 16 + (l - 16)];
    const float scale = 0.35355339059327373f;   // 1/sqrt(8)

    float macc[4] = {0.f, 0.f, 0.f, 0.f};
    float dacc = 0.f;
    int dprev = -1;
    ushort4v qv = {0, 0, 0, 0};

    for (int i = 0; i < 16; ++i) {
        const int s = __shfl(sv, i);
        const int d = __shfl(sv, 16 + i);
        if (d != dprev) {                      // wave-uniform branch
            if (dprev >= 0) {
                #pragma unroll
                for (int t = 0; t < 4; ++t)
                    atomicAdd(&msg[(size_t)dprev * 256 + l * 4 + t], macc[t]);
                if ((l & 1) == 0)
                    atomicAdd(&denom[(size_t)dprev * HEADS + (l >> 1)], dacc);
                macc[0] = macc[1] = macc[2] = macc[3] = 0.f;
                dacc = 0.f;
            }
            qv = *(const ushort4v*)(q + (size_t)d * 256 + l * 4);
            dprev = d;
        }
        const ushort4v kv = *(const ushort4v*)(k + (size_t)s * 256 + l * 4);
        const ushort4v vv = *(const ushort4v*)(v + (size_t)s * 256 + l * 4);
        const ushort4v ep = *(const ushort4v*)&ep_s[(w * 16 + i) * EP_LD + l * 4];
        float p = 0.f, m4[4];
        #pragma unroll
        for (int t = 0; t < 4; ++t) {
            const float epf = bfraw(ep[t]);
            p = fmaf(bfraw(qv[t]), bfraw(kv[t]) + epf, p);
            m4[t] = bfraw(vv[t]) + epf;
        }
        p += __shfl_xor(p, 1);                 // head = l>>1 (2 lanes/head)
        const float ex = __expf(p * scale);
        #pragma unroll
        for (int t = 0; t < 4; ++t) macc[t] = fmaf(m4[t], ex, macc[t]);
        dacc += ex;
    }
    #pragma unroll
    for (int t = 0; t < 4; ++t)
        atomicAdd(&msg[(size_t)dprev * 256 + l * 4 + t], macc[t]);
    if ((l & 1) == 0)
        atomicAdd(&denom[(size_t)dprev * HEADS + (l >> 1)], dacc);
}

// ---------------- k3: node finalize ----------------
__global__ __launch_bounds__(256) void k3_node_final(
    const float* __restrict__ msg, const float* __restrict__ denom,
    const bf16* __restrict__ skipb, float* __restrict__ out_x,
    bf16* __restrict__ xnb)
{
    const int t = blockIdx.x * 256 + threadIdx.x;
    const size_t j0 = (size_t)t * 4;
    const int n = (int)(j0 >> 8);
    const int h = ((int)(j0 & 255)) >> 3;
    const float dnm = denom[(size_t)n * HEADS + h] + 1e-16f;
    const f32x4 mv = __builtin_nontemporal_load((const f32x4*)(msg + j0));
    const ushort4v sk = *(const ushort4v*)(skipb + j0);
    f32x4 o; ushort4v ob;
    #pragma unroll
    for (int u = 0; u < 4; ++u) {
        const float xn = leaky(mv[u] / dnm + bfraw(sk[u]));
        o[u] = xn; ob[u] = rawbf(xn);
    }
    __builtin_nontemporal_store(o, (f32x4*)(out_x + j0));
    *(ushort4v*)(xnb + j0) = ob;
}

// ---------------- k4: edge MLP via MFMA (sorted tiles) ----------------
#define H_LD 584
__global__ __launch_bounds__(256) void k4_edge_mlp(
    const int* __restrict__ ssort, const int* __restrict__ dsort,
    const int* __restrict__ eidsort,
    const bf16* __restrict__ xnb, const float* __restrict__ ea,
    const bf16* __restrict__ W1Tp, const float* __restrict__ b1,
    const bf16* __restrict__ W2T, const float* __restrict__ b2,
    float* __restrict__ out_e)
{
    __shared__ unsigned short h_s[64 * H_LD];   // 74752 B
    const int tid = threadIdx.x;
    const int e0 = blockIdx.x * 64;

    { // stage h = [ea | x_s | x_d]: 4 threads/edge
        const int e = tid >> 2, t = tid & 3;
        const int sl = e0 + e;
        const int eg = eidsort[sl];
        const int s = ssort[sl], d = dsort[sl];
        const f32x4* pe = (const f32x4*)(ea + (size_t)eg * 64 + t * 16);
        unsigned short tmp[16];
        #pragma unroll
        for (int u = 0; u < 4; ++u) {
            const f32x4 vv = pe[u];
            tmp[u * 4 + 0] = rawbf(vv[0]); tmp[u * 4 + 1] = rawbf(vv[1]);
            tmp[u * 4 + 2] = rawbf(vv[2]); tmp[u * 4 + 3] = rawbf(vv[3]);
        }
        *(short8b*)&h_s[e * H_LD + t * 16]     = *(short8b*)&tmp[0];
        *(short8b*)&h_s[e * H_LD + t * 16 + 8] = *(short8b*)&tmp[8];
        const short8b* ps = (const short8b*)(xnb + (size_t)s * 256 + t * 64);
        const short8b* pd = (const short8b*)(xnb + (size_t)d * 256 + t * 64);
        #pragma unroll
        for (int u = 0; u < 8; ++u) {
            *(short8b*)&h_s[e * H_LD + 64  + t * 64 + u * 8] = ps[u];
            *(short8b*)&h_s[e * H_LD + 320 + t * 64 + u * 8] = pd[u];
        }
    }
    __syncthreads();

    const int w = tid >> 6, l = tid & 63;
    const int row = l & 15, kg = l >> 4;

    // GEMM1: [16 x 576] @ W1 -> [16 x 64]
    f32x4 acc[4];
    #pragma unroll
    for (int ct = 0; ct < 4; ++ct) {
        const float bvv = b1[ct * 16 + row];
        acc[ct] = (f32x4){bvv, bvv, bvv, bvv};
    }
    for (int kc = 0; kc < 18; ++kc) {
        const short8b af = *(const short8b*)&h_s[(w * 16 + row) * H_LD + kc * 32 + kg * 8];
        #pragma unroll
        for (int ct = 0; ct < 4; ++ct) {
            const short8b bfr = *(const short8b*)(W1Tp + (size_t)(ct * 16 + row) * 576 + kc * 32 + kg * 8);
            acc[ct] = __builtin_amdgcn_mfma_f32_16x16x32_bf16(af, bfr, acc[ct], 0, 0, 0);
        }
    }
    float ear[4][4];
    #pragma unroll
    for (int ct = 0; ct < 4; ++ct)
        #pragma unroll
        for (int r = 0; r < 4; ++r)
            ear[ct][r] = bfraw(h_s[(w * 16 + kg * 4 + r) * H_LD + ct * 16 + row]);
    __syncthreads();   // all GEMM1 LDS reads done before h2 overwrites h

    unsigned short* h2 = &h_s[w * 1152];
    #pragma unroll
    for (int ct = 0; ct < 4; ++ct)
        #pragma unroll
        for (int r = 0; r < 4; ++r)
            h2[(kg * 4 + r) * 72 + ct * 16 + row] = rawbf(leaky(acc[ct][r]));
    // same-wave LDS ops are in-order: no barrier before same-wave reads

    // GEMM2: [16 x 64] @ W2 -> [16 x 64]
    f32x4 a2[4];
    #pragma unroll
    for (int ct = 0; ct < 4; ++ct) {
        const float bvv = b2[ct * 16 + row];
        a2[ct] = (f32x4){bvv, bvv, bvv, bvv};
    }
    #pragma unroll
    for (int kc = 0; kc < 2; ++kc) {
        const short8b af = *(const short8b*)&h2[row * 72 + kc * 32 + kg * 8];
        #pragma unroll
        for (int ct = 0; ct < 4; ++ct) {
            const short8b bfr = *(const short8b*)(W2T + (size_t)(ct * 16 + row) * 64 + kc * 32 + kg * 8);
            a2[ct] = __builtin_amdgcn_mfma_f32_16x16x32_bf16(af, bfr, a2[ct], 0, 0, 0);
        }
    }
    #pragma unroll
    for (int ct = 0; ct < 4; ++ct)
        #pragma unroll
        for (int r = 0; r < 4; ++r) {
            const int eg = eidsort[e0 + w * 16 + kg * 4 + r];
            __builtin_nontemporal_store(leaky(ear[ct][r] + a2[ct][r]),
                                        out_e + (size_t)eg * 64 + ct * 16 + row);
        }
}

extern "C" void kernel_launch(void* const* d_in, const int* in_sizes, int n_in,
                              void* d_out, int out_size, void* d_ws, size_t ws_size,
                              hipStream_t stream)
{
    const float* x  = (const float*)d_in[0];
    const int*   ei = (const int*)d_in[1];
    const float* ea = (const float*)d_in[2];
    const float* Wq = (const float*)d_in[3];
    const float* bq = (const float*)d_in[4];
    const float* Wk = (const float*)d_in[5];
    const float* bk = (const float*)d_in[6];
    const float* Wv = (const float*)d_in[7];
    const float* bv = (const float*)d_in[8];
    const float* We = (const float*)d_in[9];
    const float* Ws = (const float*)d_in[10];
    const float* bs = (const float*)d_in[11];
    const float* W1 = (const float*)d_in[12];
    const float* b1 = (const float*)d_in[13];
    const float* W2 = (const float*)d_in[14];
    const float* b2 = (const float*)d_in[15];

    char* ws = (char*)d_ws;
    int*   flags  = (int*)ws;                       // 4 KB
    int*   ssort  = (int*)(ws + 4096);
    int*   dsort  = (int*)(ws + 1604096);
    int*   eids   = (int*)(ws + 3204096);
    int*   cursor = (int*)(ws + 4804096);
    bf16*  WeT    = (bf16*)(ws + 5004096);
    bf16*  W1Tp   = (bf16*)(ws + 5036864);
    bf16*  W2T    = (bf16*)(ws + 5110592);
    bf16*  WT4    = (bf16*)(ws + 5118784);
    bf16*  qb     = (bf16*)(ws + 5643072);          // xnb after k3
    bf16*  kb     = (bf16*)(ws + 31243072);
    bf16*  vb     = (bf16*)(ws + 56843072);
    float* msg    = (float*)(ws + 82443072);
    float* denom  = (float*)(ws + 133643072);

    float* out_x = (float*)d_out;
    float* out_e = out_x + (size_t)N_NODES * D_NODE;
    bf16*  skipb = (bf16*)out_e;   // bf16 skip staged in edge-out region

    hipMemsetAsync(ws + 82443072, 0, 57600000, stream);   // msg + denom
    hipMemsetAsync(cursor, 0, N_NODES * 4, stream);       // degree counters

    k0_detect<<<1, 64, 0, stream>>>(ei, flags);
    kcd_degree<<<(N_EDGES + 255) / 256, 256, 0, stream>>>(ei, flags, cursor);
    kcs_scan<<<1, 1024, 0, stream>>>(cursor);
    kct_scatter<<<(N_EDGES + 255) / 256, 256, 0, stream>>>(ei, flags, cursor, ssort, dsort, eids);

    kT_transpose<<<64, 256, 0, stream>>>(We, W1, W2, Wq, Wk, Wv, Ws, WeT, W1Tp, W2T, WT4);

    k1_node_mfma<<<(N_NODES + 63) / 64, 256, 0, stream>>>(
        x, WT4, bq, bk, bv, bs, qb, kb, vb, skipb);

    k2_attn<<<N_EDGES / 64, 256, 0, stream>>>(ssort, dsort, eids, ea, WeT, qb, kb, vb, msg, denom);

    k3_node_final<<<(N_NODES * D_NODE) / (256 * 4), 256, 0, stream>>>(
        msg, denom, skipb, out_x, qb);

    k4_edge_mlp<<<N_EDGES / 64, 256, 0, stream>>>(
        ssort, dsort, eids, qb, ea, W1Tp, b1, W2T, b2, out_e);
}

// Round 7
// 1047.916 us; speedup vs baseline: 2.1003x; 1.0494x over previous
//
#include <hip/hip_runtime.h>
#include <hip/hip_bf16.h>

// GCNBlock: TransformerConv(32 heads, dim 8, edge_dim 64) + EdgeResidualLayer
// N=50000, E=400000, D_NODE=256, D_EDGE=64. FP32 in/out, int64 edge_index.
// Internals: bf16 MFMA (16x16x32) with fp32 accumulate.
//
// Round 7: fix k1's nt-store amplification (WRITE was 410MB = 4x payload:
// per-instruction lanes were 128B-strided -> 16B masked writes into 64B
// lines, bypassing L2 write-combine). Store phase now writes one contiguous
// 4KB span per instruction (flat = u*256+tid indexing into the LDS bounce).
// Also nt loads for stream-once ea (k2/k4) and q (k2).
// Carried: CSR dst-sort, run-compressed atomic scatter, MFMA everywhere.

#define N_NODES 50000
#define N_EDGES 400000
#define D_NODE 256
#define D_EDGE 64
#define HEADS 32
#define LRELU 0.01f

typedef __hip_bfloat16 bf16;
typedef __attribute__((ext_vector_type(8))) short short8b;          // 8 bf16
typedef __attribute__((ext_vector_type(4))) float f32x4;
typedef __attribute__((ext_vector_type(4))) unsigned short ushort4v;

__device__ __forceinline__ float bf2f(bf16 v) { return __bfloat162float(v); }
__device__ __forceinline__ bf16 f2bf(float f) { return __float2bfloat16(f); }
__device__ __forceinline__ float bfraw(unsigned short u) {
    return __uint_as_float(((unsigned int)u) << 16);
}
__device__ __forceinline__ unsigned short rawbf(float f) {
    bf16 t = f2bf(f); return *(unsigned short*)&t;
}
__device__ __forceinline__ float leaky(float v) { return v >= 0.f ? v : LRELU * v; }

// ---------------- k0: index width detection (1 wave) ----------------
__global__ void k0_detect(const int* __restrict__ ei, int* __restrict__ flags)
{
    const int lane = threadIdx.x;
    const unsigned long long mz = __ballot(ei[2 * lane + 1] == 0);
    if (lane == 0) flags[0] = (__popcll(mz) >= 48) ? 1 : 0;   // 1 => int64
}

__device__ __forceinline__ void load_edge(const int* ei, int f, int i, int& s, int& d)
{
    if (f) {
        const long long* e64 = (const long long*)ei;
        s = (int)e64[i]; d = (int)e64[N_EDGES + i];
    } else {
        s = ei[i]; d = ei[N_EDGES + i];
    }
}

// ---------------- CSR build ----------------
__global__ __launch_bounds__(256) void kcd_degree(
    const int* __restrict__ ei, const int* __restrict__ flags, int* __restrict__ deg)
{
    const int i = blockIdx.x * 256 + threadIdx.x;
    if (i >= N_EDGES) return;
    int s, d; load_edge(ei, flags[0], i, s, d);
    atomicAdd(&deg[d], 1);
}

__global__ __launch_bounds__(1024) void kcs_scan(int* __restrict__ cur)  // deg -> excl. offsets
{
    __shared__ int ps[1024];
    const int t = threadIdx.x;
    const int CH = (N_NODES + 1023) / 1024;   // 49
    const int base = t * CH;
    int sum = 0;
    for (int i = 0; i < CH; ++i) {
        const int n = base + i;
        if (n < N_NODES) sum += cur[n];
    }
    ps[t] = sum;
    __syncthreads();
    for (int off = 1; off < 1024; off <<= 1) {
        const int v = (t >= off) ? ps[t - off] : 0;
        __syncthreads();
        ps[t] += v;
        __syncthreads();
    }
    int excl = (t == 0) ? 0 : ps[t - 1];
    for (int i = 0; i < CH; ++i) {
        const int n = base + i;
        if (n < N_NODES) {
            const int d = cur[n];
            cur[n] = excl;
            excl += d;
        }
    }
}

__global__ __launch_bounds__(256) void kct_scatter(
    const int* __restrict__ ei, const int* __restrict__ flags, int* __restrict__ cursor,
    int* __restrict__ ssort, int* __restrict__ dsort, int* __restrict__ eidsort)
{
    const int i = blockIdx.x * 256 + threadIdx.x;
    if (i >= N_EDGES) return;
    int s, d; load_edge(ei, flags[0], i, s, d);
    const int pos = atomicAdd(&cursor[d], 1);
    ssort[pos] = s; dsort[pos] = d; eidsort[pos] = i;
}

// ---------------- kT: weight transposes (fp32 -> bf16) ----------------
__global__ __launch_bounds__(256) void kT_transpose(
    const float* __restrict__ We, const float* __restrict__ W1, const float* __restrict__ W2,
    const float* __restrict__ Wq, const float* __restrict__ Wk,
    const float* __restrict__ Wv, const float* __restrict__ Ws,
    bf16* __restrict__ WeT, bf16* __restrict__ W1Tp, bf16* __restrict__ W2T,
    bf16* __restrict__ WT4)
{
    const int gid = blockIdx.x * 256 + threadIdx.x;
    const int gsz = gridDim.x * 256;
    for (int i = gid; i < 256 * 64; i += gsz) {
        const int n = i >> 6, k = i & 63;
        WeT[i] = f2bf(We[k * 256 + n]);
    }
    for (int i = gid; i < 64 * 576; i += gsz) {
        const int n = i / 576, kp = i % 576;
        const int k = (kp < 64) ? (512 + kp) : (kp - 64);
        W1Tp[i] = f2bf(W1[k * 64 + n]);
    }
    for (int i = gid; i < 64 * 64; i += gsz) {
        const int n = i >> 6, k = i & 63;
        W2T[i] = f2bf(W2[k * 64 + n]);
    }
    for (int i = gid; i < 4 * 256 * 256; i += gsz) {
        const int m = i >> 16, rem = i & 65535;
        const int n = rem >> 8, kk = rem & 255;
        const float* W = (m == 0) ? Wq : (m == 1) ? Wk : (m == 2) ? Wv : Ws;
        WT4[i] = f2bf(W[kk * 256 + n]);
    }
}

// ---------------- k1: node linears via MFMA (nt streams, LDS store-bounce) ----------------
#define X_LD 264
__global__ __launch_bounds__(256) void k1_node_mfma(
    const float* __restrict__ x, const bf16* __restrict__ WT4,
    const float* __restrict__ bq, const float* __restrict__ bk,
    const float* __restrict__ bv, const float* __restrict__ bs,
    bf16* __restrict__ qo, bf16* __restrict__ ko, bf16* __restrict__ vo,
    bf16* __restrict__ skipb)
{
    __shared__ unsigned short xs[64 * X_LD];   // 33792 B; reused as result bounce
    const int tid = threadIdx.x;
    const int n0 = blockIdx.x * 64;
    const int e = tid >> 2, t = tid & 3;       // node e, quarter t
    const int nmine = n0 + e;

    { // stage x tile (fp32 -> bf16), nontemporal f32x4 loads
        const f32x4* src = (const f32x4*)(x + (size_t)nmine * 256 + t * 64);
        #pragma unroll
        for (int c = 0; c < 4; ++c) {
            unsigned short tmp[16];
            if (nmine < N_NODES) {
                #pragma unroll
                for (int u = 0; u < 4; ++u) {
                    const f32x4 v = __builtin_nontemporal_load(src + c * 4 + u);
                    tmp[u * 4 + 0] = rawbf(v[0]); tmp[u * 4 + 1] = rawbf(v[1]);
                    tmp[u * 4 + 2] = rawbf(v[2]); tmp[u * 4 + 3] = rawbf(v[3]);
                }
            } else {
                #pragma unroll
                for (int u = 0; u < 16; ++u) tmp[u] = 0;
            }
            *(short8b*)&xs[e * X_LD + t * 64 + c * 16]     = *(short8b*)&tmp[0];
            *(short8b*)&xs[e * X_LD + t * 64 + c * 16 + 8] = *(short8b*)&tmp[8];
        }
    }
    __syncthreads();

    const int w = tid >> 6, l = tid & 63;
    const int row = l & 15, kg = l >> 4;
    short8b af[8];
    #pragma unroll
    for (int kc = 0; kc < 8; ++kc)
        af[kc] = *(const short8b*)&xs[(w * 16 + row) * X_LD + kc * 32 + kg * 8];

    for (int m = 0; m < 4; ++m) {
        const bf16* WT = WT4 + (size_t)m * 65536;
        const float* bias = (m == 0) ? bq : (m == 1) ? bk : (m == 2) ? bv : bs;
        __syncthreads();   // prior LDS reads (af / previous store phase) done
        #pragma unroll 4
        for (int ct = 0; ct < 16; ++ct) {
            const float bvv = bias[ct * 16 + row];
            f32x4 acc = {bvv, bvv, bvv, bvv};
            #pragma unroll
            for (int kc = 0; kc < 8; ++kc) {
                const short8b bfr = *(const short8b*)(WT + (size_t)(ct * 16 + row) * 256 + kc * 32 + kg * 8);
                acc = __builtin_amdgcn_mfma_f32_16x16x32_bf16(af[kc], bfr, acc, 0, 0, 0);
            }
            #pragma unroll
            for (int r = 0; r < 4; ++r)   // bounce: row = local node, col = output col
                xs[(w * 16 + kg * 4 + r) * X_LD + ct * 16 + row] = rawbf(acc[r]);
        }
        __syncthreads();
        { // store phase: per instruction, block writes ONE contiguous 4KB span
            bf16* dst = (m == 0) ? qo : (m == 1) ? ko : (m == 2) ? vo : skipb;
            #pragma unroll
            for (int u = 0; u < 8; ++u) {
                const int flat = u * 256 + tid;     // 16B unit within 32KB tile
                const int node = flat >> 5;         // 32 units (512B) per node
                const int col8 = (flat & 31) * 8;   // bf16 element offset
                if (n0 + node < N_NODES) {
                    const short8b vdat = *(const short8b*)&xs[node * X_LD + col8];
                    __builtin_nontemporal_store(vdat,
                        (short8b*)(dst + (size_t)(n0 + node) * 256 + col8));
                }
            }
        }
    }
}

// ---------------- k2: MFMA eproj + run-compressed attention scatter ----------------
#define EA_LD 72
#define EP_LD 264
__global__ __launch_bounds__(256) void k2_attn(
    const int* __restrict__ ssort, const int* __restrict__ dsort,
    const int* __restrict__ eidsort,
    const float* __restrict__ ea, const bf16* __restrict__ WeT,
    const bf16* __restrict__ q, const bf16* __restrict__ k, const bf16* __restrict__ v,
    float* __restrict__ msg, float* __restrict__ denom)
{
    __shared__ unsigned short ea_s[64 * EA_LD];   // 9216 B
    __shared__ unsigned short ep_s[64 * EP_LD];   // 33792 B
    const int tid = threadIdx.x;
    const int e0 = blockIdx.x * 64;

    { // stage ea tile via sorted ids (fp32 -> bf16), nt f32x4 loads
        const int e = tid >> 2, t = tid & 3;
        const int eg = eidsort[e0 + e];
        const f32x4* src = (const f32x4*)(ea + (size_t)eg * 64 + t * 16);
        unsigned short tmp[16];
        #pragma unroll
        for (int u = 0; u < 4; ++u) {
            const f32x4 vv = __builtin_nontemporal_load(src + u);
            tmp[u * 4 + 0] = rawbf(vv[0]); tmp[u * 4 + 1] = rawbf(vv[1]);
            tmp[u * 4 + 2] = rawbf(vv[2]); tmp[u * 4 + 3] = rawbf(vv[3]);
        }
        *(short8b*)&ea_s[e * EA_LD + t * 16]     = *(short8b*)&tmp[0];
        *(short8b*)&ea_s[e * EA_LD + t * 16 + 8] = *(short8b*)&tmp[8];
    }
    __syncthreads();

    const int w = tid >> 6, l = tid & 63;
    const int row = l & 15, kg = l >> 4;

    { // eproj MFMA
        const short8b af0 = *(const short8b*)&ea_s[(w * 16 + row) * EA_LD + kg * 8];
        const short8b af1 = *(const short8b*)&ea_s[(w * 16 + row) * EA_LD + 32 + kg * 8];
        #pragma unroll 4
        for (int ct = 0; ct < 16; ++ct) {
            f32x4 acc = {0.f, 0.f, 0.f, 0.f};
            const short8b b0 = *(const short8b*)(WeT + (size_t)(ct * 16 + row) * 64 + kg * 8);
            const short8b b1 = *(const short8b*)(WeT + (size_t)(ct * 16 + row) * 64 + 32 + kg * 8);
            acc = __builtin_amdgcn_mfma_f32_16x16x32_bf16(af0, b0, acc, 0, 0, 0);
            acc = __builtin_amdgcn_mfma_f32_16x16x32_bf16(af1, b1, acc, 0, 0, 0);
            #pragma unroll
            for (int r = 0; r < 4; ++r)
                ep_s[(w * 16 + kg * 4 + r) * EP_LD + ct * 16 + row] = rawbf(acc[r]);
        }
    }
    __syncthreads();

    // run-compressed attention scatter (edges dst-sorted)
    int sv = 0;
    if (l < 16)      sv = ssort[e0 + w * 16 + l];
    else if (l < 32) sv = dsort[e0 + w * 16 + (l - 16)];
    const float scale = 0.35355339059327373f;   // 1/sqrt(8)

    float macc[4] = {0.f, 0.f, 0.f, 0.f};
    float dacc = 0.f;
    int dprev = -1;
    ushort4v qv = {0, 0, 0, 0};

    for (int i = 0; i < 16; ++i) {
        const int s = __shfl(sv, i);
        const int d = __shfl(sv, 16 + i);
        if (d != dprev) {                      // wave-uniform branch
            if (dprev >= 0) {
                #pragma unroll
                for (int t = 0; t < 4; ++t)
                    atomicAdd(&msg[(size_t)dprev * 256 + l * 4 + t], macc[t]);
                if ((l & 1) == 0)
                    atomicAdd(&denom[(size_t)dprev * HEADS + (l >> 1)], dacc);
                macc[0] = macc[1] = macc[2] = macc[3] = 0.f;
                dacc = 0.f;
            }
            qv = __builtin_nontemporal_load((const ushort4v*)(q + (size_t)d * 256 + l * 4));
            dprev = d;
        }
        const ushort4v kv = *(const ushort4v*)(k + (size_t)s * 256 + l * 4);
        const ushort4v vv = *(const ushort4v*)(v + (size_t)s * 256 + l * 4);
        const ushort4v ep = *(const ushort4v*)&ep_s[(w * 16 + i) * EP_LD + l * 4];
        float p = 0.f, m4[4];
        #pragma unroll
        for (int t = 0; t < 4; ++t) {
            const float epf = bfraw(ep[t]);
            p = fmaf(bfraw(qv[t]), bfraw(kv[t]) + epf, p);
            m4[t] = bfraw(vv[t]) + epf;
        }
        p += __shfl_xor(p, 1);                 // head = l>>1 (2 lanes/head)
        const float ex = __expf(p * scale);
        #pragma unroll
        for (int t = 0; t < 4; ++t) macc[t] = fmaf(m4[t], ex, macc[t]);
        dacc += ex;
    }
    #pragma unroll
    for (int t = 0; t < 4; ++t)
        atomicAdd(&msg[(size_t)dprev * 256 + l * 4 + t], macc[t]);
    if ((l & 1) == 0)
        atomicAdd(&denom[(size_t)dprev * HEADS + (l >> 1)], dacc);
}

// ---------------- k3: node finalize ----------------
__global__ __launch_bounds__(256) void k3_node_final(
    const float* __restrict__ msg, const float* __restrict__ denom,
    const bf16* __restrict__ skipb, float* __restrict__ out_x,
    bf16* __restrict__ xnb)
{
    const int t = blockIdx.x * 256 + threadIdx.x;
    const size_t j0 = (size_t)t * 4;
    const int n = (int)(j0 >> 8);
    const int h = ((int)(j0 & 255)) >> 3;
    const float dnm = denom[(size_t)n * HEADS + h] + 1e-16f;
    const f32x4 mv = __builtin_nontemporal_load((const f32x4*)(msg + j0));
    const ushort4v sk = *(const ushort4v*)(skipb + j0);
    f32x4 o; ushort4v ob;
    #pragma unroll
    for (int u = 0; u < 4; ++u) {
        const float xn = leaky(mv[u] / dnm + bfraw(sk[u]));
        o[u] = xn; ob[u] = rawbf(xn);
    }
    __builtin_nontemporal_store(o, (f32x4*)(out_x + j0));
    *(ushort4v*)(xnb + j0) = ob;
}

// ---------------- k4: edge MLP via MFMA (sorted tiles) ----------------
#define H_LD 584
__global__ __launch_bounds__(256) void k4_edge_mlp(
    const int* __restrict__ ssort, const int* __restrict__ dsort,
    const int* __restrict__ eidsort,
    const bf16* __restrict__ xnb, const float* __restrict__ ea,
    const bf16* __restrict__ W1Tp, const float* __restrict__ b1,
    const bf16* __restrict__ W2T, const float* __restrict__ b2,
    float* __restrict__ out_e)
{
    __shared__ unsigned short h_s[64 * H_LD];   // 74752 B
    const int tid = threadIdx.x;
    const int e0 = blockIdx.x * 64;

    { // stage h = [ea | x_s | x_d]: 4 threads/edge
        const int e = tid >> 2, t = tid & 3;
        const int sl = e0 + e;
        const int eg = eidsort[sl];
        const int s = ssort[sl], d = dsort[sl];
        const f32x4* pe = (const f32x4*)(ea + (size_t)eg * 64 + t * 16);
        unsigned short tmp[16];
        #pragma unroll
        for (int u = 0; u < 4; ++u) {
            const f32x4 vv = __builtin_nontemporal_load(pe + u);
            tmp[u * 4 + 0] = rawbf(vv[0]); tmp[u * 4 + 1] = rawbf(vv[1]);
            tmp[u * 4 + 2] = rawbf(vv[2]); tmp[u * 4 + 3] = rawbf(vv[3]);
        }
        *(short8b*)&h_s[e * H_LD + t * 16]     = *(short8b*)&tmp[0];
        *(short8b*)&h_s[e * H_LD + t * 16 + 8] = *(short8b*)&tmp[8];
        const short8b* ps = (const short8b*)(xnb + (size_t)s * 256 + t * 64);
        const short8b* pd = (const short8b*)(xnb + (size_t)d * 256 + t * 64);
        #pragma unroll
        for (int u = 0; u < 8; ++u) {
            *(short8b*)&h_s[e * H_LD + 64  + t * 64 + u * 8] = ps[u];
            *(short8b*)&h_s[e * H_LD + 320 + t * 64 + u * 8] = pd[u];
        }
    }
    __syncthreads();

    const int w = tid >> 6, l = tid & 63;
    const int row = l & 15, kg = l >> 4;

    // GEMM1: [16 x 576] @ W1 -> [16 x 64]
    f32x4 acc[4];
    #pragma unroll
    for (int ct = 0; ct < 4; ++ct) {
        const float bvv = b1[ct * 16 + row];
        acc[ct] = (f32x4){bvv, bvv, bvv, bvv};
    }
    for (int kc = 0; kc < 18; ++kc) {
        const short8b af = *(const short8b*)&h_s[(w * 16 + row) * H_LD + kc * 32 + kg * 8];
        #pragma unroll
        for (int ct = 0; ct < 4; ++ct) {
            const short8b bfr = *(const short8b*)(W1Tp + (size_t)(ct * 16 + row) * 576 + kc * 32 + kg * 8);
            acc[ct] = __builtin_amdgcn_mfma_f32_16x16x32_bf16(af, bfr, acc[ct], 0, 0, 0);
        }
    }
    float ear[4][4];
    #pragma unroll
    for (int ct = 0; ct < 4; ++ct)
        #pragma unroll
        for (int r = 0; r < 4; ++r)
            ear[ct][r] = bfraw(h_s[(w * 16 + kg * 4 + r) * H_LD + ct * 16 + row]);
    __syncthreads();   // all GEMM1 LDS reads done before h2 overwrites h

    unsigned short* h2 = &h_s[w * 1152];
    #pragma unroll
    for (int ct = 0; ct < 4; ++ct)
        #pragma unroll
        for (int r = 0; r < 4; ++r)
            h2[(kg * 4 + r) * 72 + ct * 16 + row] = rawbf(leaky(acc[ct][r]));
    // same-wave LDS ops are in-order: no barrier before same-wave reads

    // GEMM2: [16 x 64] @ W2 -> [16 x 64]
    f32x4 a2[4];
    #pragma unroll
    for (int ct = 0; ct < 4; ++ct) {
        const float bvv = b2[ct * 16 + row];
        a2[ct] = (f32x4){bvv, bvv, bvv, bvv};
    }
    #pragma unroll
    for (int kc = 0; kc < 2; ++kc) {
        const short8b af = *(const short8b*)&h2[row * 72 + kc * 32 + kg * 8];
        #pragma unroll
        for (int ct = 0; ct < 4; ++ct) {
            const short8b bfr = *(const short8b*)(W2T + (size_t)(ct * 16 + row) * 64 + kc * 32 + kg * 8);
            a2[ct] = __builtin_amdgcn_mfma_f32_16x16x32_bf16(af, bfr, a2[ct], 0, 0, 0);
        }
    }
    #pragma unroll
    for (int ct = 0; ct < 4; ++ct)
        #pragma unroll
        for (int r = 0; r < 4; ++r) {
            const int eg = eidsort[e0 + w * 16 + kg * 4 + r];
            __builtin_nontemporal_store(leaky(ear[ct][r] + a2[ct][r]),
                                        out_e + (size_t)eg * 64 + ct * 16 + row);
        }
}

extern "C" void kernel_launch(void* const* d_in, const int* in_sizes, int n_in,
                              void* d_out, int out_size, void* d_ws, size_t ws_size,
                              hipStream_t stream)
{
    const float* x  = (const float*)d_in[0];
    const int*   ei = (const int*)d_in[1];
    const float* ea = (const float*)d_in[2];
    const float* Wq = (const float*)d_in[3];
    const float* bq = (const float*)d_in[4];
    const float* Wk = (const float*)d_in[5];
    const float* bk = (const float*)d_in[6];
    const float* Wv = (const float*)d_in[7];
    const float* bv = (const float*)d_in[8];
    const float* We = (const float*)d_in[9];
    const float* Ws = (const float*)d_in[10];
    const float* bs = (const float*)d_in[11];
    const float* W1 = (const float*)d_in[12];
    const float* b1 = (const float*)d_in[13];
    const float* W2 = (const float*)d_in[14];
    const float* b2 = (const float*)d_in[15];

    char* ws = (char*)d_ws;
    int*   flags  = (int*)ws;                       // 4 KB
    int*   ssort  = (int*)(ws + 4096);
    int*   dsort  = (int*)(ws + 1604096);
    int*   eids   = (int*)(ws + 3204096);
    int*   cursor = (int*)(ws + 4804096);
    bf16*  WeT    = (bf16*)(ws + 5004096);
    bf16*  W1Tp   = (bf16*)(ws + 5036864);
    bf16*  W2T    = (bf16*)(ws + 5110592);
    bf16*  WT4    = (bf16*)(ws + 5118784);
    bf16*  qb     = (bf16*)(ws + 5643072);          // xnb after k3
    bf16*  kb     = (bf16*)(ws + 31243072);
    bf16*  vb     = (bf16*)(ws + 56843072);
    float* msg    = (float*)(ws + 82443072);
    float* denom  = (float*)(ws + 133643072);

    float* out_x = (float*)d_out;
    float* out_e = out_x + (size_t)N_NODES * D_NODE;
    bf16*  skipb = (bf16*)out_e;   // bf16 skip staged in edge-out region

    hipMemsetAsync(ws + 82443072, 0, 57600000, stream);   // msg + denom
    hipMemsetAsync(cursor, 0, N_NODES * 4, stream);       // degree counters

    k0_detect<<<1, 64, 0, stream>>>(ei, flags);
    kcd_degree<<<(N_EDGES + 255) / 256, 256, 0, stream>>>(ei, flags, cursor);
    kcs_scan<<<1, 1024, 0, stream>>>(cursor);
    kct_scatter<<<(N_EDGES + 255) / 256, 256, 0, stream>>>(ei, flags, cursor, ssort, dsort, eids);

    kT_transpose<<<64, 256, 0, stream>>>(We, W1, W2, Wq, Wk, Wv, Ws, WeT, W1Tp, W2T, WT4);

    k1_node_mfma<<<(N_NODES + 63) / 64, 256, 0, stream>>>(
        x, WT4, bq, bk, bv, bs, qb, kb, vb, skipb);

    k2_attn<<<N_EDGES / 64, 256, 0, stream>>>(ssort, dsort, eids, ea, WeT, qb, kb, vb, msg, denom);

    k3_node_final<<<(N_NODES * D_NODE) / (256 * 4), 256, 0, stream>>>(
        msg, denom, skipb, out_x, qb);

    k4_edge_mlp<<<N_EDGES / 64, 256, 0, stream>>>(
        ssort, dsort, eids, qb, ea, W1Tp, b1, W2T, b2, out_e);
}